// Round 15
// baseline (1363.810 us; speedup 1.0000x reference)
//
#include <hip/hip_runtime.h>
#include <hip/hip_bf16.h>
#include <stdint.h>

typedef unsigned short u16;
typedef __attribute__((ext_vector_type(8))) short bf16x8_t;
typedef __attribute__((ext_vector_type(4))) float f32x4_t;

#define B_SZ   4096
#define N_TOT  500
#define IN_CH  8
#define NS     77
#define NE     400
#define L2_OUT 218

#define AS1C(p) ((const __attribute__((address_space(1))) void*)(p))
#define AS3(p)  ((__attribute__((address_space(3))) void*)(p))

__device__ inline u16 f2b(float f) {
  union { float f; uint32_t u; } v; v.f = f;
  uint32_t r = v.u + 0x7FFFu + ((v.u >> 16) & 1u);
  return (u16)(r >> 16);
}
__device__ inline float b2f(u16 h) {
  union { uint32_t u; float f; } v; v.u = ((uint32_t)h) << 16; return v.f;
}
__device__ inline uint32_t pk(float a, float b) {
  return (uint32_t)f2b(a) | ((uint32_t)f2b(b) << 16);
}

// ---------------- setup: CSR (parallel, deterministic, proven r10) ----------------
__global__ void k_setup(const int* __restrict__ ei, int* __restrict__ coff,
                        int* __restrict__ csrc, float* __restrict__ inv) {
  __shared__ int s_src[NE], s_dst[NE];
  __shared__ int s_cnt[NS], s_off[NS + 1];
  const int t = threadIdx.x;
  for (int e = t; e < NE; e += 128) { s_src[e] = ei[e]; s_dst[e] = ei[NE + e]; }
  __syncthreads();
  if (t < NS) {
    int c = 0;
    for (int e = 0; e < NE; ++e) c += (s_dst[e] == t && s_src[e] != t) ? 1 : 0;
    s_cnt[t] = c;
  }
  __syncthreads();
  if (t == 0) {
    int acc = 0;
    for (int i = 0; i < NS; ++i) { s_off[i] = acc; acc += s_cnt[i]; }
    s_off[NS] = acc;
  }
  __syncthreads();
  if (t < NS) {
    int o = s_off[t];
    for (int e = 0; e < NE; ++e)
      if (s_dst[e] == t && s_src[e] != t) csrc[o++] = s_src[e];
    coff[t] = s_off[t];
    inv[t] = 1.0f / (float)(s_cnt[t] + 1);
  }
  if (t == 0) coff[NS] = s_off[NS];
}

// ---------------- weight transpose + bf16 cast ----------------
__global__ void k_wt(const float* __restrict__ W, u16* __restrict__ Wt,
                     int K, int Nsrc, int Ndst) {
  __shared__ float t[32][33];
  int nk = K / 32;
  int bk = blockIdx.x % nk, bn = blockIdx.x / nk;
  int r = threadIdx.x >> 3, c4 = (threadIdx.x & 7) * 4;
  int gn = bn * 32 + c4;
  const float* src = &W[(size_t)(bk * 32 + r) * Nsrc + gn];
  if (gn + 3 < Nsrc) {
    float4 v = *(const float4*)src;
    t[r][c4] = v.x; t[r][c4+1] = v.y; t[r][c4+2] = v.z; t[r][c4+3] = v.w;
  } else {
    #pragma unroll
    for (int j = 0; j < 4; ++j) t[r][c4 + j] = (gn + j < Nsrc) ? src[j] : 0.f;
  }
  __syncthreads();
  ushort4 o;
  o.x = f2b(t[c4+0][r]); o.y = f2b(t[c4+1][r]);
  o.z = f2b(t[c4+2][r]); o.w = f2b(t[c4+3][r]);
  *(ushort4*)&Wt[(size_t)(bn * 32 + r) * K + bk * 32 + c4] = o;
}

// ---------------- fused front (proven r10) ----------------
__global__ __launch_bounds__(256)
void k_front(const float* __restrict__ x, const int* __restrict__ nid,
             const float* __restrict__ W1, const float* __restrict__ b1,
             const int* __restrict__ coff, const int* __restrict__ csrc,
             const float* __restrict__ invc,
             u16* __restrict__ h1, u16* __restrict__ ag1) {
  __shared__ float Ws[16 * 64];
  __shared__ float bs[64];
  __shared__ float xs[NS * 8];
  __shared__ float ac[NS * 16];
  __shared__ u16  hn[NS * 64];
  __shared__ int soff[NS + 1];
  __shared__ int ssrc[NE];
  __shared__ float sinv[NS];
  __shared__ int snid[NS];
  const int b = blockIdx.x, t = threadIdx.x;

  ((float4*)Ws)[t] = ((const float4*)W1)[t];
  if (t < 64) bs[t] = b1[t];
  if (t < NS) { snid[t] = nid[t]; sinv[t] = invc[t]; }
  if (t < NS + 1) soff[t] = coff[t];
  for (int i = t; i < NE; i += 256) ssrc[i] = csrc[i];
  __syncthreads();

  if (t < 2 * NS) {
    int i = t >> 1, p = t & 1;
    float4 v = *(const float4*)(x + ((size_t)b * N_TOT + snid[i]) * IN_CH + p * 4);
    *(float4*)&xs[i * 8 + p * 4] = v;
  }
  __syncthreads();

  for (int idx = t; idx < NS * 8; idx += 256) {
    int i = idx >> 3, c = idx & 7;
    float s = xs[i * 8 + c];
    ac[i * 16 + c] = s;
    for (int e = soff[i]; e < soff[i + 1]; ++e) s += xs[ssrc[e] * 8 + c];
    ac[i * 16 + 8 + c] = s * sinv[i];
  }
  __syncthreads();

  const int w = t >> 6, lane = t & 63;
  for (int i = w; i < NS; i += 4) {
    float acc = bs[lane];
    #pragma unroll
    for (int k = 0; k < 16; ++k) acc += ac[i * 16 + k] * Ws[k * 64 + lane];
    float ss = acc * acc;
    #pragma unroll
    for (int d = 1; d < 64; d <<= 1) ss += __shfl_xor(ss, d);
    float rn = 1.0f / fmaxf(sqrtf(ss), 1e-12f);
    u16 hv = f2b(fmaxf(acc * rn, 0.f));
    hn[i * 64 + lane] = hv;
    h1[((size_t)b * NS + i) * 64 + lane] = hv;
  }
  __syncthreads();
  for (int i = w; i < NS; i += 4) {
    float s = b2f(hn[i * 64 + lane]);
    for (int e = soff[i]; e < soff[i + 1]; ++e) s += b2f(hn[ssrc[e] * 64 + lane]);
    ag1[((size_t)b * NS + i) * 64 + lane] = f2b(s * sinv[i]);
  }
}

// ---------------- fused norm+relu + aggregation (proven r5) ----------------
template<int C>
__global__ __launch_bounds__(256)
void k_norm_aggr(u16* __restrict__ h, u16* __restrict__ ag,
                 const int* __restrict__ coff, const int* __restrict__ csrc,
                 const float* __restrict__ invc) {
  __shared__ u16 sh[NS * C];
  __shared__ int soff[NS + 1];
  __shared__ int ssrc[NE];
  __shared__ float sinv[NS];
  const int b = blockIdx.x, t = threadIdx.x;
  const ushort4* hb4 = (const ushort4*)(h + (size_t)b * NS * C);
  ushort4* sh4 = (ushort4*)sh;
  for (int i4 = t; i4 < NS * C / 4; i4 += 256) sh4[i4] = hb4[i4];
  for (int i = t; i < NS + 1; i += 256) soff[i] = coff[i];
  for (int i = t; i < NE; i += 256) ssrc[i] = csrc[i];
  for (int i = t; i < NS; i += 256) sinv[i] = invc[i];
  __syncthreads();
  const int w = t >> 6, lane = t & 63;
  constexpr int PER = C / 64;
  ushort4* hb4o = (ushort4*)(h + (size_t)b * NS * C);
  for (int i = w; i < NS; i += 4) {
    float v[PER]; float ss = 0.f;
    #pragma unroll
    for (int p = 0; p < PER / 4; ++p) {
      ushort4 r = *(ushort4*)&sh[i * C + lane * PER + p * 4];
      v[p*4+0] = b2f(r.x); v[p*4+1] = b2f(r.y); v[p*4+2] = b2f(r.z); v[p*4+3] = b2f(r.w);
    }
    #pragma unroll
    for (int p = 0; p < PER; ++p) ss += v[p] * v[p];
    #pragma unroll
    for (int d = 1; d < 64; d <<= 1) ss += __shfl_xor(ss, d);
    float rn = 1.0f / fmaxf(sqrtf(ss), 1e-12f);
    #pragma unroll
    for (int p = 0; p < PER / 4; ++p) {
      ushort4 o;
      o.x = f2b(fmaxf(v[p*4+0] * rn, 0.f)); o.y = f2b(fmaxf(v[p*4+1] * rn, 0.f));
      o.z = f2b(fmaxf(v[p*4+2] * rn, 0.f)); o.w = f2b(fmaxf(v[p*4+3] * rn, 0.f));
      *(ushort4*)&sh[i * C + lane * PER + p * 4] = o;
      hb4o[(i * C + lane * PER + p * 4) / 4] = o;
    }
  }
  __syncthreads();
  ushort4* ab4 = (ushort4*)(ag + (size_t)b * NS * C);
  for (int i = w; i < NS; i += 4) {
    #pragma unroll
    for (int p = 0; p < PER / 4; ++p) {
      int c0 = lane * PER + p * 4;
      ushort4 sv = *(ushort4*)&sh[i * C + c0];
      float s0 = b2f(sv.x), s1 = b2f(sv.y), s2 = b2f(sv.z), s3 = b2f(sv.w);
      for (int e = soff[i]; e < soff[i + 1]; ++e) {
        ushort4 nv = *(ushort4*)&sh[ssrc[e] * C + c0];
        s0 += b2f(nv.x); s1 += b2f(nv.y); s2 += b2f(nv.z); s3 += b2f(nv.w);
      }
      float iv = sinv[i];
      ushort4 o; o.x = f2b(s0 * iv); o.y = f2b(s1 * iv); o.z = f2b(s2 * iv); o.w = f2b(s3 * iv);
      ab4[(i * C + c0) / 4] = o;
    }
  }
}

// ---------------- row L2-norm + relu, 16B vectorized (h3, C=512) ----------------
template<int C>
__global__ void k_normrelu(u16* __restrict__ h) {
  static_assert(C == 512, "specialized for C=512");
  const int row = blockIdx.x * 4 + (threadIdx.x >> 6);
  const int lane = threadIdx.x & 63;
  u16* hr = h + (size_t)row * C + lane * 8;
  uint4 r = *(const uint4*)hr;
  float v[8];
  v[0]=b2f((u16)(r.x & 0xffff)); v[1]=b2f((u16)(r.x >> 16));
  v[2]=b2f((u16)(r.y & 0xffff)); v[3]=b2f((u16)(r.y >> 16));
  v[4]=b2f((u16)(r.z & 0xffff)); v[5]=b2f((u16)(r.z >> 16));
  v[6]=b2f((u16)(r.w & 0xffff)); v[7]=b2f((u16)(r.w >> 16));
  float ss = 0.f;
  #pragma unroll
  for (int j = 0; j < 8; ++j) ss += v[j] * v[j];
  #pragma unroll
  for (int d = 1; d < 64; d <<= 1) ss += __shfl_xor(ss, d);
  float rn = 1.0f / fmaxf(sqrtf(ss), 1e-12f);
  #pragma unroll
  for (int j = 0; j < 8; ++j) v[j] = fmaxf(v[j] * rn, 0.f);
  uint4 o;
  o.x = pk(v[0], v[1]); o.y = pk(v[2], v[3]);
  o.z = pk(v[4], v[5]); o.w = pk(v[6], v[7]);
  *(uint4*)hr = o;
}

// ---------------- MFMA GEMM, 128x128 2-phase (proven r12; conv2/L2) ----------------
template<int MODE, bool CONCAT>
__global__ __launch_bounds__(256)
void k_mfma(const u16* __restrict__ A, const u16* __restrict__ A2,
            const u16* __restrict__ Bt, const float* __restrict__ bias,
            void* __restrict__ Cv, int N, int K, int CIN,
            int kPerSplit, int Mtot) {
  __shared__ u16 As[2][128 * 32];
  __shared__ u16 Bs[2][128 * 32];
  const int t = threadIdx.x;
  const int gx = gridDim.x, gy = gridDim.y;
  const int nwg = gx * gy;
  const int orig = blockIdx.y * gx + blockIdx.x;
  const int q = nwg >> 3, r8 = nwg & 7;
  const int xcd = orig & 7, jj = orig >> 3;
  const int swzb = (xcd < r8 ? xcd * (q + 1) : r8 * (q + 1) + (xcd - r8) * q) + jj;
  const int mt_i = swzb / gy, nt_i = swzb - mt_i * gy;
  const int row0 = mt_i * 128, col0 = nt_i * 128;
  const int split = blockIdx.z;
  const int kbeg = split * kPerSplit;
  const int w = t >> 6, l = t & 63;
  const int wm = w >> 1, wn = w & 1;
  const int lr = l & 15, ls = l >> 4;
  const int s_row = t >> 2;
  const int s_c = ((t & 3) ^ ((t >> 3) & 3)) * 8;
  const int lsw = (ls ^ ((lr >> 1) & 3)) * 8;

  f32x4_t acc[4][4];
  #pragma unroll
  for (int i = 0; i < 4; ++i)
    #pragma unroll
    for (int j = 0; j < 4; ++j) acc[i][j] = (f32x4_t){0.f, 0.f, 0.f, 0.f};

  auto stage = [&](int buf, int k0) {
    const u16* abase; int astride, koff;
    if constexpr (CONCAT) {
      astride = CIN;
      if (k0 < CIN) { abase = A; koff = k0; } else { abase = A2; koff = k0 - CIN; }
    } else { abase = A; astride = K; koff = k0; }
    const u16* ga0 = abase + (size_t)(row0 + s_row) * astride + koff + s_c;
    const u16* ga1 = abase + (size_t)(row0 + 64 + s_row) * astride + koff + s_c;
    u16* la = &As[buf][w * 512];
    __builtin_amdgcn_global_load_lds(AS1C(ga0), AS3(la), 16, 0, 0);
    __builtin_amdgcn_global_load_lds(AS1C(ga1), AS3(la + 2048), 16, 0, 0);
    const u16* gb0 = Bt + (size_t)(col0 + s_row) * K + k0 + s_c;
    const u16* gb1 = Bt + (size_t)(col0 + 64 + s_row) * K + k0 + s_c;
    u16* lb = &Bs[buf][w * 512];
    __builtin_amdgcn_global_load_lds(AS1C(gb0), AS3(lb), 16, 0, 0);
    __builtin_amdgcn_global_load_lds(AS1C(gb1), AS3(lb + 2048), 16, 0, 0);
  };

  const int nsteps = kPerSplit / 32;
  stage(0, kbeg);
  __syncthreads();
  for (int s = 0; s < nsteps; ++s) {
    const int buf = s & 1;
    if (s + 1 < nsteps) stage(buf ^ 1, kbeg + (s + 1) * 32);
    bf16x8_t af[4], bfr[4];
    #pragma unroll
    for (int f = 0; f < 4; ++f) {
      af[f]  = *(const bf16x8_t*)&As[buf][(wm * 64 + f * 16 + lr) * 32 + lsw];
      bfr[f] = *(const bf16x8_t*)&Bs[buf][(wn * 64 + f * 16 + lr) * 32 + lsw];
    }
    #pragma unroll
    for (int i = 0; i < 4; ++i)
      #pragma unroll
      for (int j = 0; j < 4; ++j)
        acc[i][j] = __builtin_amdgcn_mfma_f32_16x16x32_bf16(af[i], bfr[j], acc[i][j], 0, 0, 0);
    __syncthreads();
  }

  #pragma unroll
  for (int j = 0; j < 4; ++j) {
    const int c = col0 + wn * 64 + j * 16 + lr;
    float bv = 0.f;
    if constexpr (MODE == 0) bv = bias[c];
    #pragma unroll
    for (int i = 0; i < 4; ++i) {
      const int r0 = row0 + wm * 64 + i * 16 + ls * 4;
      if constexpr (MODE == 0) {
        u16* C = (u16*)Cv;
        #pragma unroll
        for (int rr = 0; rr < 4; ++rr)
          C[(size_t)(r0 + rr) * N + c] = f2b(acc[i][j][rr] + bv);
      } else {
        float* P = (float*)Cv + (size_t)split * Mtot * N;
        #pragma unroll
        for (int rr = 0; rr < 4; ++rr)
          P[(size_t)(r0 + rr) * N + c] = acc[i][j][rr];
      }
    }
  }
}

// ---------------- MFMA GEMM, 256x256 8-phase counted-vmcnt (conv3, L1) ----------------
// 8 waves (2M x 4N), BK=64, 2 tile-buffers (128 KB LDS). Per iteration: tiles E=2i
// (phases 0-3, buf0) and O=2i+1 (phases 4-7, buf1). Register-load all wave frags of a
// tile by its 3rd phase; staging: ph3-6 -> tile 2i+2 (buf0), ph7+next ph0-2 -> tile
// 2i+3 (buf1). Waits: vmcnt(2) before ph0/ph4 (= loads issued after needed tile, in-
// order retirement); vmcnt(0) only when staging ceased. Barriers at ph0/ph4 (RAW, after
// per-wave vmcnt) and ph3/ph7 (WAR, before staging issue). 3-bit slot-XOR involution
// (128B rows): staging pre-swizzles global source, reads land 2-way conflict-free.
template<int MODE, bool CONCAT>
__global__ __launch_bounds__(512, 2)
void k_m8(const u16* __restrict__ A, const u16* __restrict__ A2,
          const u16* __restrict__ Bt, const float* __restrict__ bias,
          void* __restrict__ Cv, int N, int K, int CIN,
          int kPerSplit, int Mtot) {
  __shared__ u16 Asl[2][256 * 64];
  __shared__ u16 Bsl[2][256 * 64];
  const int t = threadIdx.x;
  const int gx = gridDim.x, gy = gridDim.y;
  const int nwg = gx * gy;
  const int orig = blockIdx.y * gx + blockIdx.x;
  const int q = nwg >> 3, r8 = nwg & 7;
  const int xcd = orig & 7, jj = orig >> 3;
  const int swzb = (xcd < r8 ? xcd * (q + 1) : r8 * (q + 1) + (xcd - r8) * q) + jj;
  const int mt_i = swzb / gy, nt_i = swzb - mt_i * gy;
  const int row0 = mt_i * 256, col0 = nt_i * 256;
  const int split = blockIdx.z;
  const int kbeg = split * kPerSplit;
  const int w = t >> 6, l = t & 63;
  const int wm = w >> 2, wn = w & 3;            // wave tile 128(M) x 64(N)
  const int lr = l & 15, ls = l >> 4;           // frag row-in-16, k-slot (0..3)
  const int lr7 = lr & 7;
  const int srw = w * 8 + (l >> 3);             // staging row within 64-row instr
  const int scl = ((l & 7) ^ (l >> 3)) * 8;     // pre-swizzled source chunk (elems)

  f32x4_t acc[8][4];
  #pragma unroll
  for (int i = 0; i < 8; ++i)
    #pragma unroll
    for (int j = 0; j < 4; ++j) acc[i][j] = (f32x4_t){0.f, 0.f, 0.f, 0.f};

  bf16x8_t Ar[8][2];
  bf16x8_t Br[4][2];

  // part 0: A rows 0-127; 1: A rows 128-255; 2: B rows 0-127; 3: B rows 128-255.
  auto stagePart = [&](int tile, int part) {
    const int bb = tile & 1;
    const int k0 = kbeg + tile * 64;
    if (part < 2) {
      const u16* abase; int astride, koff;
      if constexpr (CONCAT) {
        astride = CIN;
        if (k0 < CIN) { abase = A; koff = k0; } else { abase = A2; koff = k0 - CIN; }
      } else { abase = A; astride = K; koff = k0; }
      const int rb = part * 128;
      const u16* g0 = abase + (size_t)(row0 + rb + srw) * astride + koff + scl;
      const u16* g1 = abase + (size_t)(row0 + rb + 64 + srw) * astride + koff + scl;
      u16* d = &Asl[bb][rb * 64 + w * 512];
      __builtin_amdgcn_global_load_lds(AS1C(g0), AS3(d), 16, 0, 0);
      __builtin_amdgcn_global_load_lds(AS1C(g1), AS3(d + 4096), 16, 0, 0);
    } else {
      const int rb = (part - 2) * 128;
      const u16* g0 = Bt + (size_t)(col0 + rb + srw) * K + k0 + scl;
      const u16* g1 = Bt + (size_t)(col0 + rb + 64 + srw) * K + k0 + scl;
      u16* d = &Bsl[bb][rb * 64 + w * 512];
      __builtin_amdgcn_global_load_lds(AS1C(g0), AS3(d), 16, 0, 0);
      __builtin_amdgcn_global_load_lds(AS1C(g1), AS3(d + 4096), 16, 0, 0);
    }
  };

#define RD_ALO(BB)                                                            \
  _Pragma("unroll")                                                           \
  for (int mf = 0; mf < 4; ++mf) {                                            \
    _Pragma("unroll")                                                         \
    for (int kh = 0; kh < 2; ++kh)                                            \
      Ar[mf][kh] = *(const bf16x8_t*)&Asl[BB][(wm * 128 + mf * 16 + lr) * 64  \
                                             + ((kh * 4 + ls) ^ lr7) * 8];    \
  }
#define RD_AHI(BB)                                                            \
  _Pragma("unroll")                                                           \
  for (int mf = 0; mf < 4; ++mf) {                                            \
    _Pragma("unroll")                                                         \
    for (int kh = 0; kh < 2; ++kh)                                            \
      Ar[4 + mf][kh] = *(const bf16x8_t*)&Asl[BB][(wm * 128 + 64 + mf * 16 + lr) * 64 \
                                                 + ((kh * 4 + ls) ^ lr7) * 8];\
  }
#define RD_BLO(BB)                                                            \
  _Pragma("unroll")                                                           \
  for (int nf = 0; nf < 2; ++nf) {                                            \
    _Pragma("unroll")                                                         \
    for (int kh = 0; kh < 2; ++kh)                                            \
      Br[nf][kh] = *(const bf16x8_t*)&Bsl[BB][(wn * 64 + nf * 16 + lr) * 64   \
                                             + ((kh * 4 + ls) ^ lr7) * 8];    \
  }
#define RD_BHI(BB)                                                            \
  _Pragma("unroll")                                                           \
  for (int nf = 0; nf < 2; ++nf) {                                            \
    _Pragma("unroll")                                                         \
    for (int kh = 0; kh < 2; ++kh)                                            \
      Br[2 + nf][kh] = *(const bf16x8_t*)&Bsl[BB][(wn * 64 + 32 + nf * 16 + lr) * 64 \
                                                 + ((kh * 4 + ls) ^ lr7) * 8];\
  }
#define DO_QUAD(QM, QN)                                                       \
  __builtin_amdgcn_s_setprio(1);                                              \
  {                                                                           \
    _Pragma("unroll")                                                         \
    for (int mf = 0; mf < 4; ++mf) {                                          \
      _Pragma("unroll")                                                       \
      for (int nf = 0; nf < 2; ++nf) {                                        \
        _Pragma("unroll")                                                     \
        for (int kh = 0; kh < 2; ++kh)                                        \
          acc[(QM) * 4 + mf][(QN) * 2 + nf] =                                 \
              __builtin_amdgcn_mfma_f32_16x16x32_bf16(                        \
                  Ar[(QM) * 4 + mf][kh], Br[(QN) * 2 + nf][kh],               \
                  acc[(QM) * 4 + mf][(QN) * 2 + nf], 0, 0, 0);                \
      }                                                                       \
    }                                                                         \
  }                                                                           \
  __builtin_amdgcn_s_setprio(0);

  const int NT = kPerSplit / 64;                // even for all call sites
  // prologue: tile0 fully + tile1 part0
  stagePart(0, 0); stagePart(0, 1); stagePart(0, 2); stagePart(0, 3);
  stagePart(1, 0);

  const int NI = NT / 2;
  for (int i = 0; i < NI; ++i) {
    const int tO = 2 * i + 1;
    const bool s2 = (2 * i + 2) < NT;
    // ---- phase 0 ----
    asm volatile("s_waitcnt vmcnt(2)" ::: "memory");
    __builtin_amdgcn_s_barrier();
    asm volatile("" ::: "memory");
    stagePart(tO, 1);
    RD_ALO(0) RD_BLO(0)
    DO_QUAD(0, 0)
    // ---- phase 1 ----
    stagePart(tO, 2);
    RD_AHI(0)
    DO_QUAD(1, 0)
    // ---- phase 2 ----
    stagePart(tO, 3);
    RD_BHI(0)
    DO_QUAD(0, 1)
    // ---- phase 3 ----
    __builtin_amdgcn_s_barrier();
    asm volatile("" ::: "memory");
    if (s2) stagePart(2 * i + 2, 0);
    DO_QUAD(1, 1)
    // ---- phase 4 ----
    if (s2) { asm volatile("s_waitcnt vmcnt(2)" ::: "memory"); }
    else    { asm volatile("s_waitcnt vmcnt(0)" ::: "memory"); }
    __builtin_amdgcn_s_barrier();
    asm volatile("" ::: "memory");
    if (s2) stagePart(2 * i + 2, 1);
    RD_ALO(1) RD_BLO(1)
    DO_QUAD(0, 0)
    // ---- phase 5 ----
    if (s2) stagePart(2 * i + 2, 2);
    RD_AHI(1)
    DO_QUAD(1, 0)
    // ---- phase 6 ----
    if (s2) stagePart(2 * i + 2, 3);
    RD_BHI(1)
    DO_QUAD(0, 1)
    // ---- phase 7 ----
    __builtin_amdgcn_s_barrier();
    asm volatile("" ::: "memory");
    if (2 * i + 3 < NT) stagePart(2 * i + 3, 0);
    DO_QUAD(1, 1)
  }

  // epilogue: C/D mapping col=lane&15, row=(lane>>4)*4+reg (proven)
  #pragma unroll
  for (int j = 0; j < 4; ++j) {
    const int c = col0 + wn * 64 + j * 16 + lr;
    float bv = 0.f;
    if constexpr (MODE == 0) bv = bias[c];
    #pragma unroll
    for (int i = 0; i < 8; ++i) {
      const int r0 = row0 + wm * 128 + i * 16 + ls * 4;
      if constexpr (MODE == 0) {
        u16* C = (u16*)Cv;
        #pragma unroll
        for (int rr = 0; rr < 4; ++rr)
          C[(size_t)(r0 + rr) * N + c] = f2b(acc[i][j][rr] + bv);
      } else {
        float* P = (float*)Cv + (size_t)split * Mtot * N;
        #pragma unroll
        for (int rr = 0; rr < 4; ++rr)
          P[(size_t)(r0 + rr) * N + c] = acc[i][j][rr];
      }
    }
  }
#undef RD_ALO
#undef RD_AHI
#undef RD_BLO
#undef RD_BHI
#undef DO_QUAD
}

// ---------------- split-K reduce (L1): y1 = bf16(relu(sum + bias)), N=1024 ----------------
__global__ void k_red4(const float* __restrict__ P, const float* __restrict__ bias,
                       u16* __restrict__ y, int MN) {
  int i = blockIdx.x * 256 + threadIdx.x;
  if (i * 4 >= MN) return;
  const float4* p = (const float4*)P;
  int stride = MN / 4;
  float4 a = p[i], b = p[i + stride], c = p[i + 2 * stride], d = p[i + 3 * stride];
  float4 bv = *(const float4*)&bias[(i * 4) & 1023];
  ushort4 o;
  o.x = f2b(fmaxf(a.x + b.x + c.x + d.x + bv.x, 0.f));
  o.y = f2b(fmaxf(a.y + b.y + c.y + d.y + bv.y, 0.f));
  o.z = f2b(fmaxf(a.z + b.z + c.z + d.z + bv.z, 0.f));
  o.w = f2b(fmaxf(a.w + b.w + c.w + d.w + bv.w, 0.f));
  *(ushort4*)&y[i * 4] = o;
}

// ---------------- fused tail: L2 split-K reduce + bias + relu + L3 (218 -> 2) ----------------
__global__ void k_tail(const float* __restrict__ P, const float* __restrict__ L2bias,
                       const float* __restrict__ w, const float* __restrict__ b,
                       float* __restrict__ out, int nb) {
  const int row = blockIdx.x * 4 + (threadIdx.x >> 6);
  const int lane = threadIdx.x & 63;
  if (row >= nb) return;
  const int MN = nb * 256;
  float s0 = 0.f, s1 = 0.f;
  #pragma unroll
  for (int j = 0; j < 4; ++j) {
    int col = lane + 64 * j;
    if (col < L2_OUT) {
      int idx = row * 256 + col;
      float v = P[idx] + P[idx + MN] + P[idx + 2 * MN] + P[idx + 3 * MN];
      v = fmaxf(v + L2bias[col], 0.f);
      s0 += v * w[col * 2];
      s1 += v * w[col * 2 + 1];
    }
  }
  #pragma unroll
  for (int d = 1; d < 64; d <<= 1) { s0 += __shfl_xor(s0, d); s1 += __shfl_xor(s1, d); }
  if (lane == 0) { out[(size_t)row * 2] = s0 + b[0]; out[(size_t)row * 2 + 1] = s1 + b[1]; }
}

extern "C" void kernel_launch(void* const* d_in, const int* in_sizes, int n_in,
                              void* d_out, int out_size, void* d_ws, size_t ws_size,
                              hipStream_t stream) {
  const float* x   = (const float*)d_in[0];
  const int*   nid = (const int*)d_in[1];
  const int*   ei  = (const int*)d_in[2];
  const float* W1  = (const float*)d_in[3];  const float* b1 = (const float*)d_in[4];
  const float* W2  = (const float*)d_in[5];  const float* b2 = (const float*)d_in[6];
  const float* W3  = (const float*)d_in[7];  const float* b3 = (const float*)d_in[8];
  const float* L1w = (const float*)d_in[9];  const float* L1b = (const float*)d_in[10];
  const float* L2w = (const float*)d_in[11]; const float* L2b = (const float*)d_in[12];
  const float* L3w = (const float*)d_in[13]; const float* L3b = (const float*)d_in[14];
  float* out = (float*)d_out;

  char* ws = (char*)d_ws;
  u16* Wt2  = (u16*)ws;
  u16* Wt3  = (u16*)(ws + 65536);
  u16* WtL1 = (u16*)(ws + 589824);
  u16* WtL2 = (u16*)(ws + 81330176);
  size_t WOFF = 81854464;
  int*   coff = (int*)(ws + WOFF);
  int*   csrc = coff + 80;
  float* invc = (float*)(csrc + 400);
  size_t CHUNK0 = WOFF + 4096;

  // Bc must keep rows = Bc*77 divisible by 256 -> Bc multiple of 256.
  int Bc = 4096;
  while (Bc > 256 && CHUNK0 + (size_t)Bc * 157696 > ws_size) Bc >>= 1;

  char* r1 = ws + CHUNK0;                       // h2 -> y1b + Pc/Pc2
  char* r2 = r1 + (size_t)Bc * 39424;           // h1 -> ag2
  char* r3 = r2 + (size_t)Bc * 39424;           // ag1 -> h3

  k_setup<<<1, 128, 0, stream>>>(ei, coff, csrc, invc);
  k_wt<<<(128/32)*(256/32),    256, 0, stream>>>(W2,  Wt2,  128,   256,  256);
  k_wt<<<(512/32)*(512/32),    256, 0, stream>>>(W3,  Wt3,  512,   512,  512);
  k_wt<<<(39424/32)*(1024/32), 256, 0, stream>>>(L1w, WtL1, 39424, 1024, 1024);
  k_wt<<<(1024/32)*(256/32),   256, 0, stream>>>(L2w, WtL2, 1024,  218,  256);

  for (int b0 = 0; b0 < B_SZ; b0 += Bc) {
    const int nb = Bc;
    const int rows = nb * NS;
    const int mt = rows / 128;
    u16* h1  = (u16*)r2;
    u16* ag1 = (u16*)r3;
    u16* h2  = (u16*)r1;
    u16* ag2 = (u16*)r2;
    u16* h3  = (u16*)r3;
    u16* y1b = (u16*)r1;
    float* Pc  = (float*)(r1 + (size_t)nb * 4096);
    float* Pc2 = (float*)(r1 + (size_t)nb * 4096);
    const float* xb = x + (size_t)b0 * N_TOT * IN_CH;

    // fused: gather + aggr0 + conv1 + norm/relu + aggr1
    k_front<<<nb, 256, 0, stream>>>(xb, nid, W1, b1, coff, csrc, invc, h1, ag1);

    // conv2: 64 -> 256 (proven 128^2), raw h2; then fused norm+aggr -> ag2
    k_mfma<0, true><<<dim3(mt, 2, 1), 256, 0, stream>>>(
        h1, ag1, Wt2, b2, h2, 256, 128, 64, 128, rows);
    k_norm_aggr<256><<<nb, 256, 0, stream>>>(h2, ag2, coff, csrc, invc);

    // conv3: 256 -> 512 (NEW 256^2 8-phase), then norm+relu in place
    k_m8<0, true><<<dim3(rows / 256, 2, 1), 512, 0, stream>>>(
        h2, ag2, Wt3, b3, h3, 512, 512, 256, 512, rows);
    k_normrelu<512><<<rows / 4, 256, 0, stream>>>(h3);

    // L1: (nb x 39424) (NEW 256^2 8-phase, split-K 4) -> reduce+bias+relu -> bf16 y1
    k_m8<1, false><<<dim3(nb / 256, 4, 4), 512, 0, stream>>>(
        h3, nullptr, WtL1, nullptr, Pc, 1024, 39424, 0, 9856, nb);
    k_red4<<<nb, 256, 0, stream>>>(Pc, L1b, y1b, nb * 1024);

    // L2: (nb x 1024) split-K 4 (proven 128^2, N padded 256) -> fused tail
    k_mfma<1, false><<<dim3(nb / 128, 2, 4), 256, 0, stream>>>(
        y1b, nullptr, WtL2, nullptr, Pc2, 256, 1024, 0, 256, nb);
    k_tail<<<(nb + 3) / 4, 256, 0, stream>>>(Pc2, L2b, L3w, L3b, out + (size_t)b0 * 2, nb);
  }
}

// Round 16
// 1298.398 us; speedup vs baseline: 1.0504x; 1.0504x over previous
//
#include <hip/hip_runtime.h>
#include <hip/hip_bf16.h>
#include <stdint.h>

typedef unsigned short u16;
typedef __attribute__((ext_vector_type(8))) short bf16x8_t;
typedef __attribute__((ext_vector_type(4))) float f32x4_t;

#define B_SZ   4096
#define N_TOT  500
#define IN_CH  8
#define NS     77
#define NE     400
#define L2_OUT 218

#define AS1C(p) ((const __attribute__((address_space(1))) void*)(p))
#define AS3(p)  ((__attribute__((address_space(3))) void*)(p))

__device__ inline u16 f2b(float f) {
  union { float f; uint32_t u; } v; v.f = f;
  uint32_t r = v.u + 0x7FFFu + ((v.u >> 16) & 1u);
  return (u16)(r >> 16);
}
__device__ inline float b2f(u16 h) {
  union { uint32_t u; float f; } v; v.u = ((uint32_t)h) << 16; return v.f;
}
__device__ inline uint32_t pk(float a, float b) {
  return (uint32_t)f2b(a) | ((uint32_t)f2b(b) << 16);
}

// ---------------- setup: CSR (parallel, deterministic, proven r10) ----------------
__global__ void k_setup(const int* __restrict__ ei, int* __restrict__ coff,
                        int* __restrict__ csrc, float* __restrict__ inv) {
  __shared__ int s_src[NE], s_dst[NE];
  __shared__ int s_cnt[NS], s_off[NS + 1];
  const int t = threadIdx.x;
  for (int e = t; e < NE; e += 128) { s_src[e] = ei[e]; s_dst[e] = ei[NE + e]; }
  __syncthreads();
  if (t < NS) {
    int c = 0;
    for (int e = 0; e < NE; ++e) c += (s_dst[e] == t && s_src[e] != t) ? 1 : 0;
    s_cnt[t] = c;
  }
  __syncthreads();
  if (t == 0) {
    int acc = 0;
    for (int i = 0; i < NS; ++i) { s_off[i] = acc; acc += s_cnt[i]; }
    s_off[NS] = acc;
  }
  __syncthreads();
  if (t < NS) {
    int o = s_off[t];
    for (int e = 0; e < NE; ++e)
      if (s_dst[e] == t && s_src[e] != t) csrc[o++] = s_src[e];
    coff[t] = s_off[t];
    inv[t] = 1.0f / (float)(s_cnt[t] + 1);
  }
  if (t == 0) coff[NS] = s_off[NS];
}

// ---------------- weight transpose + bf16 cast ----------------
__global__ void k_wt(const float* __restrict__ W, u16* __restrict__ Wt,
                     int K, int Nsrc, int Ndst) {
  __shared__ float t[32][33];
  int nk = K / 32;
  int bk = blockIdx.x % nk, bn = blockIdx.x / nk;
  int r = threadIdx.x >> 3, c4 = (threadIdx.x & 7) * 4;
  int gn = bn * 32 + c4;
  const float* src = &W[(size_t)(bk * 32 + r) * Nsrc + gn];
  if (gn + 3 < Nsrc) {
    float4 v = *(const float4*)src;
    t[r][c4] = v.x; t[r][c4+1] = v.y; t[r][c4+2] = v.z; t[r][c4+3] = v.w;
  } else {
    #pragma unroll
    for (int j = 0; j < 4; ++j) t[r][c4 + j] = (gn + j < Nsrc) ? src[j] : 0.f;
  }
  __syncthreads();
  ushort4 o;
  o.x = f2b(t[c4+0][r]); o.y = f2b(t[c4+1][r]);
  o.z = f2b(t[c4+2][r]); o.w = f2b(t[c4+3][r]);
  *(ushort4*)&Wt[(size_t)(bn * 32 + r) * K + bk * 32 + c4] = o;
}

// ---------------- fused front (proven r10) ----------------
__global__ __launch_bounds__(256)
void k_front(const float* __restrict__ x, const int* __restrict__ nid,
             const float* __restrict__ W1, const float* __restrict__ b1,
             const int* __restrict__ coff, const int* __restrict__ csrc,
             const float* __restrict__ invc,
             u16* __restrict__ h1, u16* __restrict__ ag1) {
  __shared__ float Ws[16 * 64];
  __shared__ float bs[64];
  __shared__ float xs[NS * 8];
  __shared__ float ac[NS * 16];
  __shared__ u16  hn[NS * 64];
  __shared__ int soff[NS + 1];
  __shared__ int ssrc[NE];
  __shared__ float sinv[NS];
  __shared__ int snid[NS];
  const int b = blockIdx.x, t = threadIdx.x;

  ((float4*)Ws)[t] = ((const float4*)W1)[t];
  if (t < 64) bs[t] = b1[t];
  if (t < NS) { snid[t] = nid[t]; sinv[t] = invc[t]; }
  if (t < NS + 1) soff[t] = coff[t];
  for (int i = t; i < NE; i += 256) ssrc[i] = csrc[i];
  __syncthreads();

  if (t < 2 * NS) {
    int i = t >> 1, p = t & 1;
    float4 v = *(const float4*)(x + ((size_t)b * N_TOT + snid[i]) * IN_CH + p * 4);
    *(float4*)&xs[i * 8 + p * 4] = v;
  }
  __syncthreads();

  for (int idx = t; idx < NS * 8; idx += 256) {
    int i = idx >> 3, c = idx & 7;
    float s = xs[i * 8 + c];
    ac[i * 16 + c] = s;
    for (int e = soff[i]; e < soff[i + 1]; ++e) s += xs[ssrc[e] * 8 + c];
    ac[i * 16 + 8 + c] = s * sinv[i];
  }
  __syncthreads();

  const int w = t >> 6, lane = t & 63;
  for (int i = w; i < NS; i += 4) {
    float acc = bs[lane];
    #pragma unroll
    for (int k = 0; k < 16; ++k) acc += ac[i * 16 + k] * Ws[k * 64 + lane];
    float ss = acc * acc;
    #pragma unroll
    for (int d = 1; d < 64; d <<= 1) ss += __shfl_xor(ss, d);
    float rn = 1.0f / fmaxf(sqrtf(ss), 1e-12f);
    u16 hv = f2b(fmaxf(acc * rn, 0.f));
    hn[i * 64 + lane] = hv;
    h1[((size_t)b * NS + i) * 64 + lane] = hv;
  }
  __syncthreads();
  for (int i = w; i < NS; i += 4) {
    float s = b2f(hn[i * 64 + lane]);
    for (int e = soff[i]; e < soff[i + 1]; ++e) s += b2f(hn[ssrc[e] * 64 + lane]);
    ag1[((size_t)b * NS + i) * 64 + lane] = f2b(s * sinv[i]);
  }
}

// ---------------- fused norm+relu + aggregation (proven r5) ----------------
template<int C>
__global__ __launch_bounds__(256)
void k_norm_aggr(u16* __restrict__ h, u16* __restrict__ ag,
                 const int* __restrict__ coff, const int* __restrict__ csrc,
                 const float* __restrict__ invc) {
  __shared__ u16 sh[NS * C];
  __shared__ int soff[NS + 1];
  __shared__ int ssrc[NE];
  __shared__ float sinv[NS];
  const int b = blockIdx.x, t = threadIdx.x;
  const ushort4* hb4 = (const ushort4*)(h + (size_t)b * NS * C);
  ushort4* sh4 = (ushort4*)sh;
  for (int i4 = t; i4 < NS * C / 4; i4 += 256) sh4[i4] = hb4[i4];
  for (int i = t; i < NS + 1; i += 256) soff[i] = coff[i];
  for (int i = t; i < NE; i += 256) ssrc[i] = csrc[i];
  for (int i = t; i < NS; i += 256) sinv[i] = invc[i];
  __syncthreads();
  const int w = t >> 6, lane = t & 63;
  constexpr int PER = C / 64;
  ushort4* hb4o = (ushort4*)(h + (size_t)b * NS * C);
  for (int i = w; i < NS; i += 4) {
    float v[PER]; float ss = 0.f;
    #pragma unroll
    for (int p = 0; p < PER / 4; ++p) {
      ushort4 r = *(ushort4*)&sh[i * C + lane * PER + p * 4];
      v[p*4+0] = b2f(r.x); v[p*4+1] = b2f(r.y); v[p*4+2] = b2f(r.z); v[p*4+3] = b2f(r.w);
    }
    #pragma unroll
    for (int p = 0; p < PER; ++p) ss += v[p] * v[p];
    #pragma unroll
    for (int d = 1; d < 64; d <<= 1) ss += __shfl_xor(ss, d);
    float rn = 1.0f / fmaxf(sqrtf(ss), 1e-12f);
    #pragma unroll
    for (int p = 0; p < PER / 4; ++p) {
      ushort4 o;
      o.x = f2b(fmaxf(v[p*4+0] * rn, 0.f)); o.y = f2b(fmaxf(v[p*4+1] * rn, 0.f));
      o.z = f2b(fmaxf(v[p*4+2] * rn, 0.f)); o.w = f2b(fmaxf(v[p*4+3] * rn, 0.f));
      *(ushort4*)&sh[i * C + lane * PER + p * 4] = o;
      hb4o[(i * C + lane * PER + p * 4) / 4] = o;
    }
  }
  __syncthreads();
  ushort4* ab4 = (ushort4*)(ag + (size_t)b * NS * C);
  for (int i = w; i < NS; i += 4) {
    #pragma unroll
    for (int p = 0; p < PER / 4; ++p) {
      int c0 = lane * PER + p * 4;
      ushort4 sv = *(ushort4*)&sh[i * C + c0];
      float s0 = b2f(sv.x), s1 = b2f(sv.y), s2 = b2f(sv.z), s3 = b2f(sv.w);
      for (int e = soff[i]; e < soff[i + 1]; ++e) {
        ushort4 nv = *(ushort4*)&sh[ssrc[e] * C + c0];
        s0 += b2f(nv.x); s1 += b2f(nv.y); s2 += b2f(nv.z); s3 += b2f(nv.w);
      }
      float iv = sinv[i];
      ushort4 o; o.x = f2b(s0 * iv); o.y = f2b(s1 * iv); o.z = f2b(s2 * iv); o.w = f2b(s3 * iv);
      ab4[(i * C + c0) / 4] = o;
    }
  }
}

// ---------------- row L2-norm + relu, 16B vectorized (h3, C=512) ----------------
template<int C>
__global__ void k_normrelu(u16* __restrict__ h) {
  static_assert(C == 512, "specialized for C=512");
  const int row = blockIdx.x * 4 + (threadIdx.x >> 6);
  const int lane = threadIdx.x & 63;
  u16* hr = h + (size_t)row * C + lane * 8;
  uint4 r = *(const uint4*)hr;
  float v[8];
  v[0]=b2f((u16)(r.x & 0xffff)); v[1]=b2f((u16)(r.x >> 16));
  v[2]=b2f((u16)(r.y & 0xffff)); v[3]=b2f((u16)(r.y >> 16));
  v[4]=b2f((u16)(r.z & 0xffff)); v[5]=b2f((u16)(r.z >> 16));
  v[6]=b2f((u16)(r.w & 0xffff)); v[7]=b2f((u16)(r.w >> 16));
  float ss = 0.f;
  #pragma unroll
  for (int j = 0; j < 8; ++j) ss += v[j] * v[j];
  #pragma unroll
  for (int d = 1; d < 64; d <<= 1) ss += __shfl_xor(ss, d);
  float rn = 1.0f / fmaxf(sqrtf(ss), 1e-12f);
  #pragma unroll
  for (int j = 0; j < 8; ++j) v[j] = fmaxf(v[j] * rn, 0.f);
  uint4 o;
  o.x = pk(v[0], v[1]); o.y = pk(v[2], v[3]);
  o.z = pk(v[4], v[5]); o.w = pk(v[6], v[7]);
  *(uint4*)hr = o;
}

// ---------------- MFMA GEMM, 128x128 2-phase (proven r12), slot-XOR LDS involution ----------------
// MODE 0: bf16 out + bias. MODE 1: f32 partial at split offset.
template<int MODE, bool CONCAT>
__global__ __launch_bounds__(256)
void k_mfma(const u16* __restrict__ A, const u16* __restrict__ A2,
            const u16* __restrict__ Bt, const float* __restrict__ bias,
            void* __restrict__ Cv, int N, int K, int CIN,
            int kPerSplit, int Mtot) {
  __shared__ u16 As[2][128 * 32];
  __shared__ u16 Bs[2][128 * 32];
  const int t = threadIdx.x;
  const int gx = gridDim.x, gy = gridDim.y;
  const int nwg = gx * gy;
  const int orig = blockIdx.y * gx + blockIdx.x;
  const int q = nwg >> 3, r8 = nwg & 7;
  const int xcd = orig & 7, jj = orig >> 3;
  const int swzb = (xcd < r8 ? xcd * (q + 1) : r8 * (q + 1) + (xcd - r8) * q) + jj;
  const int mt_i = swzb / gy, nt_i = swzb - mt_i * gy;
  const int row0 = mt_i * 128, col0 = nt_i * 128;
  const int split = blockIdx.z;
  const int kbeg = split * kPerSplit;
  const int w = t >> 6, l = t & 63;
  const int wm = w >> 1, wn = w & 1;
  const int lr = l & 15, ls = l >> 4;
  const int s_row = t >> 2;
  const int s_c = ((t & 3) ^ ((t >> 3) & 3)) * 8;
  const int lsw = (ls ^ ((lr >> 1) & 3)) * 8;

  f32x4_t acc[4][4];
  #pragma unroll
  for (int i = 0; i < 4; ++i)
    #pragma unroll
    for (int j = 0; j < 4; ++j) acc[i][j] = (f32x4_t){0.f, 0.f, 0.f, 0.f};

  auto stage = [&](int buf, int k0) {
    const u16* abase; int astride, koff;
    if constexpr (CONCAT) {
      astride = CIN;
      if (k0 < CIN) { abase = A; koff = k0; } else { abase = A2; koff = k0 - CIN; }
    } else { abase = A; astride = K; koff = k0; }
    const u16* ga0 = abase + (size_t)(row0 + s_row) * astride + koff + s_c;
    const u16* ga1 = abase + (size_t)(row0 + 64 + s_row) * astride + koff + s_c;
    u16* la = &As[buf][w * 512];
    __builtin_amdgcn_global_load_lds(AS1C(ga0), AS3(la), 16, 0, 0);
    __builtin_amdgcn_global_load_lds(AS1C(ga1), AS3(la + 2048), 16, 0, 0);
    const u16* gb0 = Bt + (size_t)(col0 + s_row) * K + k0 + s_c;
    const u16* gb1 = Bt + (size_t)(col0 + 64 + s_row) * K + k0 + s_c;
    u16* lb = &Bs[buf][w * 512];
    __builtin_amdgcn_global_load_lds(AS1C(gb0), AS3(lb), 16, 0, 0);
    __builtin_amdgcn_global_load_lds(AS1C(gb1), AS3(lb + 2048), 16, 0, 0);
  };

  const int nsteps = kPerSplit / 32;
  stage(0, kbeg);
  __syncthreads();
  for (int s = 0; s < nsteps; ++s) {
    const int buf = s & 1;
    if (s + 1 < nsteps) stage(buf ^ 1, kbeg + (s + 1) * 32);
    bf16x8_t af[4], bfr[4];
    #pragma unroll
    for (int f = 0; f < 4; ++f) {
      af[f]  = *(const bf16x8_t*)&As[buf][(wm * 64 + f * 16 + lr) * 32 + lsw];
      bfr[f] = *(const bf16x8_t*)&Bs[buf][(wn * 64 + f * 16 + lr) * 32 + lsw];
    }
    #pragma unroll
    for (int i = 0; i < 4; ++i)
      #pragma unroll
      for (int j = 0; j < 4; ++j)
        acc[i][j] = __builtin_amdgcn_mfma_f32_16x16x32_bf16(af[i], bfr[j], acc[i][j], 0, 0, 0);
    __syncthreads();
  }

  #pragma unroll
  for (int j = 0; j < 4; ++j) {
    const int c = col0 + wn * 64 + j * 16 + lr;
    float bv = 0.f;
    if constexpr (MODE == 0) bv = bias[c];
    #pragma unroll
    for (int i = 0; i < 4; ++i) {
      const int r0 = row0 + wm * 64 + i * 16 + ls * 4;
      if constexpr (MODE == 0) {
        u16* C = (u16*)Cv;
        #pragma unroll
        for (int rr = 0; rr < 4; ++rr)
          C[(size_t)(r0 + rr) * N + c] = f2b(acc[i][j][rr] + bv);
      } else {
        float* P = (float*)Cv + (size_t)split * Mtot * N;
        #pragma unroll
        for (int rr = 0; rr < 4; ++rr)
          P[(size_t)(r0 + rr) * N + c] = acc[i][j][rr];
      }
    }
  }
}

// ---------------- split-K reduce (L1): y1 = bf16(relu(sum + bias)), N=1024 ----------------
__global__ void k_red4(const float* __restrict__ P, const float* __restrict__ bias,
                       u16* __restrict__ y, int MN) {
  int i = blockIdx.x * 256 + threadIdx.x;
  if (i * 4 >= MN) return;
  const float4* p = (const float4*)P;
  int stride = MN / 4;
  float4 a = p[i], b = p[i + stride], c = p[i + 2 * stride], d = p[i + 3 * stride];
  float4 bv = *(const float4*)&bias[(i * 4) & 1023];
  ushort4 o;
  o.x = f2b(fmaxf(a.x + b.x + c.x + d.x + bv.x, 0.f));
  o.y = f2b(fmaxf(a.y + b.y + c.y + d.y + bv.y, 0.f));
  o.z = f2b(fmaxf(a.z + b.z + c.z + d.z + bv.z, 0.f));
  o.w = f2b(fmaxf(a.w + b.w + c.w + d.w + bv.w, 0.f));
  *(ushort4*)&y[i * 4] = o;
}

// ---------------- fused tail: L2 split-K reduce + bias + relu + L3 (218 -> 2) ----------------
__global__ void k_tail(const float* __restrict__ P, const float* __restrict__ L2bias,
                       const float* __restrict__ w, const float* __restrict__ b,
                       float* __restrict__ out, int nb) {
  const int row = blockIdx.x * 4 + (threadIdx.x >> 6);
  const int lane = threadIdx.x & 63;
  if (row >= nb) return;
  const int MN = nb * 256;
  float s0 = 0.f, s1 = 0.f;
  #pragma unroll
  for (int j = 0; j < 4; ++j) {
    int col = lane + 64 * j;
    if (col < L2_OUT) {
      int idx = row * 256 + col;
      float v = P[idx] + P[idx + MN] + P[idx + 2 * MN] + P[idx + 3 * MN];
      v = fmaxf(v + L2bias[col], 0.f);
      s0 += v * w[col * 2];
      s1 += v * w[col * 2 + 1];
    }
  }
  #pragma unroll
  for (int d = 1; d < 64; d <<= 1) { s0 += __shfl_xor(s0, d); s1 += __shfl_xor(s1, d); }
  if (lane == 0) { out[(size_t)row * 2] = s0 + b[0]; out[(size_t)row * 2 + 1] = s1 + b[1]; }
}

extern "C" void kernel_launch(void* const* d_in, const int* in_sizes, int n_in,
                              void* d_out, int out_size, void* d_ws, size_t ws_size,
                              hipStream_t stream) {
  const float* x   = (const float*)d_in[0];
  const int*   nid = (const int*)d_in[1];
  const int*   ei  = (const int*)d_in[2];
  const float* W1  = (const float*)d_in[3];  const float* b1 = (const float*)d_in[4];
  const float* W2  = (const float*)d_in[5];  const float* b2 = (const float*)d_in[6];
  const float* W3  = (const float*)d_in[7];  const float* b3 = (const float*)d_in[8];
  const float* L1w = (const float*)d_in[9];  const float* L1b = (const float*)d_in[10];
  const float* L2w = (const float*)d_in[11]; const float* L2b = (const float*)d_in[12];
  const float* L3w = (const float*)d_in[13]; const float* L3b = (const float*)d_in[14];
  float* out = (float*)d_out;

  char* ws = (char*)d_ws;
  u16* Wt2  = (u16*)ws;
  u16* Wt3  = (u16*)(ws + 65536);
  u16* WtL1 = (u16*)(ws + 589824);
  u16* WtL2 = (u16*)(ws + 81330176);
  size_t WOFF = 81854464;
  int*   coff = (int*)(ws + WOFF);
  int*   csrc = coff + 80;
  float* invc = (float*)(csrc + 400);
  size_t CHUNK0 = WOFF + 4096;

  int Bc = 4096;
  while (Bc > 128 && CHUNK0 + (size_t)Bc * 157696 > ws_size) Bc >>= 1;

  char* r1 = ws + CHUNK0;                       // h2 -> y1b + Pc/Pc2
  char* r2 = r1 + (size_t)Bc * 39424;           // h1 -> ag2
  char* r3 = r2 + (size_t)Bc * 39424;           // ag1 -> h3

  k_setup<<<1, 128, 0, stream>>>(ei, coff, csrc, invc);
  k_wt<<<(128/32)*(256/32),    256, 0, stream>>>(W2,  Wt2,  128,   256,  256);
  k_wt<<<(512/32)*(512/32),    256, 0, stream>>>(W3,  Wt3,  512,   512,  512);
  k_wt<<<(39424/32)*(1024/32), 256, 0, stream>>>(L1w, WtL1, 39424, 1024, 1024);
  k_wt<<<(1024/32)*(256/32),   256, 0, stream>>>(L2w, WtL2, 1024,  218,  256);

  for (int b0 = 0; b0 < B_SZ; b0 += Bc) {
    const int nb = Bc;
    const int rows = nb * NS;
    const int mt = rows / 128;
    u16* h1  = (u16*)r2;
    u16* ag1 = (u16*)r3;
    u16* h2  = (u16*)r1;
    u16* ag2 = (u16*)r2;
    u16* h3  = (u16*)r3;
    u16* y1b = (u16*)r1;
    float* Pc  = (float*)(r1 + (size_t)nb * 4096);
    float* Pc2 = (float*)(r1 + (size_t)nb * 4096);  // reuse after red4 consumed Pc
    const float* xb = x + (size_t)b0 * N_TOT * IN_CH;

    // fused: gather + aggr0 + conv1 + norm/relu + aggr1
    k_front<<<nb, 256, 0, stream>>>(xb, nid, W1, b1, coff, csrc, invc, h1, ag1);

    // conv2: 64 -> 256, raw h2; then fused norm+aggr -> ag2
    k_mfma<0, true><<<dim3(mt, 2, 1), 256, 0, stream>>>(
        h1, ag1, Wt2, b2, h2, 256, 128, 64, 128, rows);
    k_norm_aggr<256><<<nb, 256, 0, stream>>>(h2, ag2, coff, csrc, invc);

    // conv3: 256 -> 512, then norm+relu in place (16B vectorized)
    k_mfma<0, true><<<dim3(mt, 4, 1), 256, 0, stream>>>(
        h2, ag2, Wt3, b3, h3, 512, 512, 256, 512, rows);
    k_normrelu<512><<<rows / 4, 256, 0, stream>>>(h3);

    // L1: (nb x 39424) split-K 4 -> reduce+bias+relu -> bf16 y1
    k_mfma<1, false><<<dim3(nb / 128, 8, 4), 256, 0, stream>>>(
        h3, nullptr, WtL1, nullptr, Pc, 1024, 39424, 0, 9856, nb);
    k_red4<<<nb, 256, 0, stream>>>(Pc, L1b, y1b, nb * 1024);

    // L2: (nb x 1024) split-K 4 (N padded 256) -> fused tail (reduce+bias+relu+L3)
    k_mfma<1, false><<<dim3(nb / 128, 2, 4), 256, 0, stream>>>(
        y1b, nullptr, WtL2, nullptr, Pc2, 256, 1024, 0, 256, nb);
    k_tail<<<(nb + 3) / 4, 256, 0, stream>>>(Pc2, L2b, L3w, L3b, out + (size_t)b0 * 2, nb);
  }
}